// Round 7
// baseline (419.317 us; speedup 1.0000x reference)
//
#include <hip/hip_runtime.h>
#include <math.h>

typedef unsigned long long u64;
typedef int    i32x4 __attribute__((ext_vector_type(4)));

#define T_LEN   4096
#define VOCAB   50257
#define TOP_M   4
#define WEIGHT  0.5f
#define HASH_B  1315423911ull

#define CHAIN_BLOCKS  32
#define CHAIN_THREADS 128

// ---------------- Fused chain + scatter ----------------
// Stages ids into LDS, computes slot[t] into LDS, then one thread per position t
// walks its slot-chain (register-resident table state). Emitted deltas are
// atomicAdd'ed directly into out (which already holds the copied logits).
__global__ void __launch_bounds__(CHAIN_THREADS) chain_scatter_kernel(const int* __restrict__ ids,
                                                                      float* __restrict__ out) {
    __shared__ int sids[T_LEN];
    __shared__ int s[T_LEN];
    {
        i32x4* dst4 = (i32x4*)sids;
        const i32x4* g4 = (const i32x4*)ids;
        for (int i = threadIdx.x; i < T_LEN / 4; i += CHAIN_THREADS) dst4[i] = g4[i];
    }
    __syncthreads();
    const u64 B1 = HASH_B;
    const u64 B2 = B1 * B1;
    const u64 B3 = B2 * B1;
    for (int i = threadIdx.x; i < T_LEN; i += CHAIN_THREADS) {
        if (i < 3) { s[i] = -1; continue; }
        u64 fp = (u64)(unsigned)(sids[i - 3] + 1) * B3
               + (u64)(unsigned)(sids[i - 2] + 1) * B2
               + (u64)(unsigned)(sids[i - 1] + 1) * B1
               + (u64)(unsigned)(sids[i]     + 1);
        s[i] = (int)(fp & 0xFFFFull);
    }
    __syncthreads();

    int t = blockIdx.x * CHAIN_THREADS + threadIdx.x;
    if (t < 3) return;                       // never chain heads (slot = -1)
    const int mys = s[t];

    // register-resident slot state
    u64 key = 0ull;
    int tk[TOP_M] = {0, 0, 0, 0};
    int cs[TOP_M] = {0, 0, 0, 0};
    bool dead = false;

    const i32x4* s4 = (const i32x4*)s;
    for (int qb = 0; qb < T_LEN / 4; qb += 8) {
        i32x4 v[8];
        #pragma unroll
        for (int u = 0; u < 8; ++u) v[u] = s4[qb + u];     // broadcast ds_read_b128 ×8
        bool any = false;
        #pragma unroll
        for (int u = 0; u < 8; ++u)
            any |= (v[u].x == mys) | (v[u].y == mys) | (v[u].z == mys) | (v[u].w == mys);
        if (!any) continue;

        #pragma unroll
        for (int u = 0; u < 8; ++u) {
            #pragma unroll
            for (int j = 0; j < 4; ++j) {
                int sv = (j == 0) ? v[u].x : (j == 1) ? v[u].y : (j == 2) ? v[u].z : v[u].w;
                if (sv != mys) continue;
                int tp = (qb + u) * 4 + j;
                if (tp < t) { dead = true; continue; }
                if (dead) continue;

                // ---- process chain member at position tp ----
                u64 wk = (u64)(unsigned)(sids[tp - 3] + 1) * B3
                       + (u64)(unsigned)(sids[tp - 2] + 1) * B2
                       + (u64)(unsigned)(sids[tp - 1] + 1) * B1
                       + (u64)(unsigned)(sids[tp]     + 1) + 1ull;
                bool key_match = (key == wk);

                int tot = 0;
                #pragma unroll
                for (int m = 0; m < TOP_M; ++m) tot += (tk[m] > 0) ? cs[m] : 0;
                bool emit = key_match && (tot > 0);

                if (emit) {
                    float denom = fmaxf((float)tot, 1.0f);
                    #pragma unroll
                    for (int m = 0; m < TOP_M; ++m) {
                        if (tk[m] > 0 && cs[m] > 0) {
                            float p = fmaxf(1e-9f, (float)cs[m] / denom);
                            atomicAdd(out + (size_t)tp * VOCAB + (tk[m] - 1),
                                      logf(p) * WEIGHT);
                        }
                    }
                }

                if (tp < T_LEN - 1) {                      // do_upd = active & has_next
                    if (!key_match) {
                        #pragma unroll
                        for (int m = 0; m < TOP_M; ++m) { tk[m] = 0; cs[m] = 0; }
                    }
                    key = wk;
                    int ntp1 = sids[tp + 1] + 1;

                    int ins = -1;
                    #pragma unroll
                    for (int m = 0; m < TOP_M; ++m) if (ins < 0 && tk[m] == ntp1) ins = m;
                    bool matched = (ins >= 0);
                    if (ins < 0) {
                        #pragma unroll
                        for (int m = 0; m < TOP_M; ++m) if (ins < 0 && tk[m] == 0) ins = m;
                    }
                    if (ins < 0) {
                        int best = cs[0]; ins = 0;
                        #pragma unroll
                        for (int m = 1; m < TOP_M; ++m) if (cs[m] < best) { best = cs[m]; ins = m; }
                    }
                    int cur = 0;
                    #pragma unroll
                    for (int m = 0; m < TOP_M; ++m) if (m == ins) cur = cs[m];
                    int new_cnt = matched ? min(65535, cur + 1) : 1;
                    #pragma unroll
                    for (int m = 0; m < TOP_M; ++m) if (m == ins) { tk[m] = ntp1; cs[m] = new_cnt; }
                }
            }
        }
        if (dead) break;   // not a head: everything after my first earlier twin is irrelevant
    }
}

extern "C" void kernel_launch(void* const* d_in, const int* in_sizes, int n_in,
                              void* d_out, int out_size, void* d_ws, size_t ws_size,
                              hipStream_t stream) {
    const float* logits = (const float*)d_in[0];
    const int*   ids    = (const int*)d_in[1];
    float*       out    = (float*)d_out;
    (void)d_ws; (void)ws_size;

    // 1) dense move via runtime D2D path (SDMA/optimized blit, graph-capture-legal)
    hipMemcpyAsync(out, logits, (size_t)out_size * sizeof(float),
                   hipMemcpyDeviceToDevice, stream);

    // 2) sparse deltas straight into out
    chain_scatter_kernel<<<CHAIN_BLOCKS, CHAIN_THREADS, 0, stream>>>(ids, out);
}

// Round 8
// 367.161 us; speedup vs baseline: 1.1421x; 1.1421x over previous
//
#include <hip/hip_runtime.h>
#include <math.h>

typedef unsigned long long u64;
typedef float  f32x4 __attribute__((ext_vector_type(4)));
typedef int    i32x4 __attribute__((ext_vector_type(4)));

#define T_LEN   4096
#define VOCAB   50257
#define TOP_M   4
#define WEIGHT  0.5f
#define HASH_B  1315423911ull

#define CHAIN_BLOCKS  32
#define CHAIN_THREADS 128

#define COPY_THREADS  256
#define COPY_ILP      2

// ---------------- Fused chain + scatter ----------------
// Stages ids into LDS, computes slot[t] into LDS, then one thread per position t
// walks its slot-chain (register-resident table state). Emitted deltas are
// atomicAdd'ed directly into out (which already holds the copied logits).
__global__ void __launch_bounds__(CHAIN_THREADS) chain_scatter_kernel(const int* __restrict__ ids,
                                                                      float* __restrict__ out) {
    __shared__ int sids[T_LEN];
    __shared__ int s[T_LEN];
    {
        i32x4* dst4 = (i32x4*)sids;
        const i32x4* g4 = (const i32x4*)ids;
        for (int i = threadIdx.x; i < T_LEN / 4; i += CHAIN_THREADS) dst4[i] = g4[i];
    }
    __syncthreads();
    const u64 B1 = HASH_B;
    const u64 B2 = B1 * B1;
    const u64 B3 = B2 * B1;
    for (int i = threadIdx.x; i < T_LEN; i += CHAIN_THREADS) {
        if (i < 3) { s[i] = -1; continue; }
        u64 fp = (u64)(unsigned)(sids[i - 3] + 1) * B3
               + (u64)(unsigned)(sids[i - 2] + 1) * B2
               + (u64)(unsigned)(sids[i - 1] + 1) * B1
               + (u64)(unsigned)(sids[i]     + 1);
        s[i] = (int)(fp & 0xFFFFull);
    }
    __syncthreads();

    int t = blockIdx.x * CHAIN_THREADS + threadIdx.x;
    if (t < 3) return;                       // never chain heads (slot = -1)
    const int mys = s[t];

    u64 key = 0ull;
    int tk[TOP_M] = {0, 0, 0, 0};
    int cs[TOP_M] = {0, 0, 0, 0};
    bool dead = false;

    const i32x4* s4 = (const i32x4*)s;
    for (int qb = 0; qb < T_LEN / 4; qb += 8) {
        i32x4 v[8];
        #pragma unroll
        for (int u = 0; u < 8; ++u) v[u] = s4[qb + u];     // broadcast ds_read_b128 ×8
        bool any = false;
        #pragma unroll
        for (int u = 0; u < 8; ++u)
            any |= (v[u].x == mys) | (v[u].y == mys) | (v[u].z == mys) | (v[u].w == mys);
        if (!any) continue;

        #pragma unroll
        for (int u = 0; u < 8; ++u) {
            #pragma unroll
            for (int j = 0; j < 4; ++j) {
                int sv = (j == 0) ? v[u].x : (j == 1) ? v[u].y : (j == 2) ? v[u].z : v[u].w;
                if (sv != mys) continue;
                int tp = (qb + u) * 4 + j;
                if (tp < t) { dead = true; continue; }
                if (dead) continue;

                u64 wk = (u64)(unsigned)(sids[tp - 3] + 1) * B3
                       + (u64)(unsigned)(sids[tp - 2] + 1) * B2
                       + (u64)(unsigned)(sids[tp - 1] + 1) * B1
                       + (u64)(unsigned)(sids[tp]     + 1) + 1ull;
                bool key_match = (key == wk);

                int tot = 0;
                #pragma unroll
                for (int m = 0; m < TOP_M; ++m) tot += (tk[m] > 0) ? cs[m] : 0;
                bool emit = key_match && (tot > 0);

                if (emit) {
                    float denom = fmaxf((float)tot, 1.0f);
                    #pragma unroll
                    for (int m = 0; m < TOP_M; ++m) {
                        if (tk[m] > 0 && cs[m] > 0) {
                            float p = fmaxf(1e-9f, (float)cs[m] / denom);
                            atomicAdd(out + (size_t)tp * VOCAB + (tk[m] - 1),
                                      logf(p) * WEIGHT);
                        }
                    }
                }

                if (tp < T_LEN - 1) {
                    if (!key_match) {
                        #pragma unroll
                        for (int m = 0; m < TOP_M; ++m) { tk[m] = 0; cs[m] = 0; }
                    }
                    key = wk;
                    int ntp1 = sids[tp + 1] + 1;

                    int ins = -1;
                    #pragma unroll
                    for (int m = 0; m < TOP_M; ++m) if (ins < 0 && tk[m] == ntp1) ins = m;
                    bool matched = (ins >= 0);
                    if (ins < 0) {
                        #pragma unroll
                        for (int m = 0; m < TOP_M; ++m) if (ins < 0 && tk[m] == 0) ins = m;
                    }
                    if (ins < 0) {
                        int best = cs[0]; ins = 0;
                        #pragma unroll
                        for (int m = 1; m < TOP_M; ++m) if (cs[m] < best) { best = cs[m]; ins = m; }
                    }
                    int cur = 0;
                    #pragma unroll
                    for (int m = 0; m < TOP_M; ++m) if (m == ins) cur = cs[m];
                    int new_cnt = matched ? min(65535, cur + 1) : 1;
                    #pragma unroll
                    for (int m = 0; m < TOP_M; ++m) if (m == ins) { tk[m] = ntp1; cs[m] = new_cnt; }
                }
            }
        }
        if (dead) break;
    }
}

// ---------------- Dense copy: flat, ILP=2, nt loads then nt stores ----------------
// Each block covers 512 contiguous float4s; thread handles base+tid and
// base+tid+256 — two independent loads in flight before the dependent stores.
__global__ void __launch_bounds__(COPY_THREADS) copy_kernel(const f32x4* __restrict__ src,
                                                            f32x4* __restrict__ dst,
                                                            size_t n4) {
    size_t base = (size_t)blockIdx.x * (COPY_THREADS * COPY_ILP) + threadIdx.x;
    size_t k0 = base;
    size_t k1 = base + COPY_THREADS;
    bool b0 = k0 < n4, b1 = k1 < n4;
    f32x4 v0, v1;
    if (b0) v0 = __builtin_nontemporal_load(&src[k0]);
    if (b1) v1 = __builtin_nontemporal_load(&src[k1]);
    if (b0) __builtin_nontemporal_store(v0, &dst[k0]);
    if (b1) __builtin_nontemporal_store(v1, &dst[k1]);
}

// scalar tail (out_size % 4), launched only if needed
__global__ void copy_tail_kernel(const float* __restrict__ src, float* __restrict__ dst,
                                 size_t start, size_t n_total) {
    size_t k = start + threadIdx.x;
    if (k < n_total) dst[k] = src[k];
}

extern "C" void kernel_launch(void* const* d_in, const int* in_sizes, int n_in,
                              void* d_out, int out_size, void* d_ws, size_t ws_size,
                              hipStream_t stream) {
    const float* logits = (const float*)d_in[0];
    const int*   ids    = (const int*)d_in[1];
    float*       out    = (float*)d_out;
    (void)d_ws; (void)ws_size;

    size_t n_total = (size_t)out_size;
    size_t n4 = n_total / 4;
    size_t nblk = (n4 + COPY_THREADS * COPY_ILP - 1) / (COPY_THREADS * COPY_ILP);
    copy_kernel<<<(uint32_t)nblk, COPY_THREADS, 0, stream>>>((const f32x4*)logits,
                                                             (f32x4*)out, n4);
    if (n_total - n4 * 4)
        copy_tail_kernel<<<1, 64, 0, stream>>>(logits, out, n4 * 4, n_total);

    chain_scatter_kernel<<<CHAIN_BLOCKS, CHAIN_THREADS, 0, stream>>>(ids, out);
}

// Round 9
// 364.201 us; speedup vs baseline: 1.1513x; 1.0081x over previous
//
#include <hip/hip_runtime.h>
#include <math.h>

typedef unsigned long long u64;
typedef float  f32x4 __attribute__((ext_vector_type(4)));
typedef int    i32x4 __attribute__((ext_vector_type(4)));

#define T_LEN   4096
#define VOCAB   50257
#define TOP_M   4
#define WEIGHT  0.5f
#define HASH_B  1315423911ull

#define CHAIN_BLOCKS  32
#define CHAIN_THREADS 128
#define COPY_THREADS  256

// ---------------- Kernel 1: per-slot chains -> idxs/vals tables in ws ----------------
__global__ void __launch_bounds__(CHAIN_THREADS) chain_kernel(const int* __restrict__ ids,
                                                              int* __restrict__ idxs,
                                                              float* __restrict__ vals) {
    __shared__ int sids[T_LEN];
    __shared__ int s[T_LEN];
    {
        i32x4* dst4 = (i32x4*)sids;
        const i32x4* g4 = (const i32x4*)ids;
        for (int i = threadIdx.x; i < T_LEN / 4; i += CHAIN_THREADS) dst4[i] = g4[i];
    }
    __syncthreads();
    const u64 B1 = HASH_B;
    const u64 B2 = B1 * B1;
    const u64 B3 = B2 * B1;
    for (int i = threadIdx.x; i < T_LEN; i += CHAIN_THREADS) {
        if (i < 3) { s[i] = -1; continue; }
        u64 fp = (u64)(unsigned)(sids[i - 3] + 1) * B3
               + (u64)(unsigned)(sids[i - 2] + 1) * B2
               + (u64)(unsigned)(sids[i - 1] + 1) * B1
               + (u64)(unsigned)(sids[i]     + 1);
        s[i] = (int)(fp & 0xFFFFull);
    }
    __syncthreads();

    int t = blockIdx.x * CHAIN_THREADS + threadIdx.x;
    if (t < 3) {
        *(i32x4*)&idxs[t * 4] = (i32x4){0, 0, 0, 0};
        *(f32x4*)&vals[t * 4] = (f32x4){0.f, 0.f, 0.f, 0.f};
        return;
    }
    const int mys = s[t];

    u64 key = 0ull;
    int tk[TOP_M] = {0, 0, 0, 0};
    int cs[TOP_M] = {0, 0, 0, 0};
    bool dead = false;

    const i32x4* s4 = (const i32x4*)s;
    for (int qb = 0; qb < T_LEN / 4; qb += 8) {
        i32x4 v[8];
        #pragma unroll
        for (int u = 0; u < 8; ++u) v[u] = s4[qb + u];     // broadcast ds_read_b128 ×8
        bool any = false;
        #pragma unroll
        for (int u = 0; u < 8; ++u)
            any |= (v[u].x == mys) | (v[u].y == mys) | (v[u].z == mys) | (v[u].w == mys);
        if (!any) continue;

        #pragma unroll
        for (int u = 0; u < 8; ++u) {
            #pragma unroll
            for (int j = 0; j < 4; ++j) {
                int sv = (j == 0) ? v[u].x : (j == 1) ? v[u].y : (j == 2) ? v[u].z : v[u].w;
                if (sv != mys) continue;
                int tp = (qb + u) * 4 + j;
                if (tp < t) { dead = true; continue; }
                if (dead) continue;

                u64 wk = (u64)(unsigned)(sids[tp - 3] + 1) * B3
                       + (u64)(unsigned)(sids[tp - 2] + 1) * B2
                       + (u64)(unsigned)(sids[tp - 1] + 1) * B1
                       + (u64)(unsigned)(sids[tp]     + 1) + 1ull;
                bool key_match = (key == wk);

                int tot = 0;
                #pragma unroll
                for (int m = 0; m < TOP_M; ++m) tot += (tk[m] > 0) ? cs[m] : 0;
                bool emit = key_match && (tot > 0);
                float denom = fmaxf((float)tot, 1.0f);

                int   oi[TOP_M];
                float ov[TOP_M];
                #pragma unroll
                for (int m = 0; m < TOP_M; ++m) {
                    bool ok = emit && (tk[m] > 0) && (cs[m] > 0);
                    float p = fmaxf(1e-9f, (float)cs[m] / denom);
                    ov[m] = ok ? (logf(p) * WEIGHT) : 0.0f;
                    oi[m] = ok ? (tk[m] - 1) : 0;
                }
                *(i32x4*)&idxs[tp * 4] = (i32x4){oi[0], oi[1], oi[2], oi[3]};
                *(f32x4*)&vals[tp * 4] = (f32x4){ov[0], ov[1], ov[2], ov[3]};

                if (tp < T_LEN - 1) {
                    if (!key_match) {
                        #pragma unroll
                        for (int m = 0; m < TOP_M; ++m) { tk[m] = 0; cs[m] = 0; }
                    }
                    key = wk;
                    int ntp1 = sids[tp + 1] + 1;

                    int ins = -1;
                    #pragma unroll
                    for (int m = 0; m < TOP_M; ++m) if (ins < 0 && tk[m] == ntp1) ins = m;
                    bool matched = (ins >= 0);
                    if (ins < 0) {
                        #pragma unroll
                        for (int m = 0; m < TOP_M; ++m) if (ins < 0 && tk[m] == 0) ins = m;
                    }
                    if (ins < 0) {
                        int best = cs[0]; ins = 0;
                        #pragma unroll
                        for (int m = 1; m < TOP_M; ++m) if (cs[m] < best) { best = cs[m]; ins = m; }
                    }
                    int cur = 0;
                    #pragma unroll
                    for (int m = 0; m < TOP_M; ++m) if (m == ins) cur = cs[m];
                    int new_cnt = matched ? min(65535, cur + 1) : 1;
                    #pragma unroll
                    for (int m = 0; m < TOP_M; ++m) if (m == ins) { tk[m] = ntp1; cs[m] = new_cnt; }
                }
            }
        }
        if (dead) break;
    }
}

// ---------------- Kernel 2: fused copy + delta-apply (flat, 1 float4/thread, nt) ----------------
// Thread k copies float4 k and folds in its row's <=4 sparse deltas in-register.
// Unused table entries are (idx=0, val=0.0f) so blind "add val where idx==col"
// is a value-level no-op. Rows are 50257 floats => a float4 may straddle two
// rows (rare: ~1/12.5K threads); last float4 never straddles (4096 full rows).
__global__ void __launch_bounds__(COPY_THREADS) copy_apply_kernel(const f32x4* __restrict__ src,
                                                                  f32x4* __restrict__ dst,
                                                                  const i32x4* __restrict__ idxs4,
                                                                  const f32x4* __restrict__ vals4) {
    size_t k = (size_t)blockIdx.x * COPY_THREADS + threadIdx.x;
    f32x4 v = __builtin_nontemporal_load(&src[k]);

    unsigned e = (unsigned)(k * 4);        // max 205,852,668 < 2^31
    unsigned r = e / VOCAB;                // magic-mul division
    unsigned c = e - r * VOCAB;

    if (c + 3 < VOCAB) {                   // fast path: all 4 cols in row r
        i32x4 id = idxs4[r];
        f32x4 vl = vals4[r];
        #pragma unroll
        for (int j = 0; j < 4; ++j) {
            int col = (int)(c + j);
            float add = 0.0f;
            add += (id.x == col) ? vl.x : 0.0f;
            add += (id.y == col) ? vl.y : 0.0f;
            add += (id.z == col) ? vl.z : 0.0f;
            add += (id.w == col) ? vl.w : 0.0f;
            v[j] += add;
        }
    } else {                               // straddle: cols split between r and r+1
        #pragma unroll
        for (int j = 0; j < 4; ++j) {
            unsigned cj = c + j;
            unsigned rj = r + (cj >= VOCAB ? 1u : 0u);
            int col = (int)(cj >= VOCAB ? cj - VOCAB : cj);
            i32x4 id = idxs4[rj];
            f32x4 vl = vals4[rj];
            float add = 0.0f;
            add += (id.x == col) ? vl.x : 0.0f;
            add += (id.y == col) ? vl.y : 0.0f;
            add += (id.z == col) ? vl.z : 0.0f;
            add += (id.w == col) ? vl.w : 0.0f;
            v[j] += add;
        }
    }
    __builtin_nontemporal_store(v, &dst[k]);
}

extern "C" void kernel_launch(void* const* d_in, const int* in_sizes, int n_in,
                              void* d_out, int out_size, void* d_ws, size_t ws_size,
                              hipStream_t stream) {
    const float* logits = (const float*)d_in[0];
    const int*   ids    = (const int*)d_in[1];
    float*       out    = (float*)d_out;

    char* ws = (char*)d_ws;
    int*   idxs = (int*)(ws);              // 16384*4 = 64 KB
    float* vals = (float*)(ws + 65536);    // 64 KB

    chain_kernel<<<CHAIN_BLOCKS, CHAIN_THREADS, 0, stream>>>(ids, idxs, vals);

    size_t n4 = (size_t)out_size / 4;      // 51,463,168 — exact, no tail
    size_t nblk = (n4 + COPY_THREADS - 1) / COPY_THREADS;
    copy_apply_kernel<<<(uint32_t)nblk, COPY_THREADS, 0, stream>>>(
        (const f32x4*)logits, (f32x4*)out, (const i32x4*)idxs, (const f32x4*)vals);
}

// Round 10
// 287.040 us; speedup vs baseline: 1.4608x; 1.2688x over previous
//
#include <hip/hip_runtime.h>
#include <math.h>

typedef unsigned long long u64;
typedef float  f32x4 __attribute__((ext_vector_type(4)));
typedef int    i32x4 __attribute__((ext_vector_type(4)));

#define T_LEN   4096
#define VOCAB   50257
#define TOP_M   4
#define WEIGHT  0.5f
#define HASH_B  1315423911ull

#define MEGA_THREADS  256
#define CHAIN_BLOCKS  16          // 16 * 256 = 4096 = T_LEN

// ---------------- Mega-kernel: blocks 0..15 = chain, rest = dense nt-copy ----------------
// Chain and copy are data-independent; fusing them into one dispatch hides the
// chain's ~15 us under the 201K copy blocks. Delta scatter runs as a separate
// (ordered) kernel afterwards.
__global__ void __launch_bounds__(MEGA_THREADS) mega_kernel(
        const int* __restrict__ ids,
        const f32x4* __restrict__ src, f32x4* __restrict__ dst, size_t n4,
        int* __restrict__ idxs, float* __restrict__ vals) {
    __shared__ int sids[T_LEN];
    __shared__ int s[T_LEN];

    if (blockIdx.x >= CHAIN_BLOCKS) {
        // ---- copy role: flat, one float4/thread, nt load + nt store (measured best) ----
        size_t k = (size_t)(blockIdx.x - CHAIN_BLOCKS) * MEGA_THREADS + threadIdx.x;
        if (k < n4) {
            f32x4 v = __builtin_nontemporal_load(&src[k]);
            __builtin_nontemporal_store(v, &dst[k]);
        }
        return;
    }

    // ---- chain role ----
    {
        i32x4* dst4 = (i32x4*)sids;
        const i32x4* g4 = (const i32x4*)ids;
        for (int i = threadIdx.x; i < T_LEN / 4; i += MEGA_THREADS) dst4[i] = g4[i];
    }
    __syncthreads();
    const u64 B1 = HASH_B;
    const u64 B2 = B1 * B1;
    const u64 B3 = B2 * B1;
    for (int i = threadIdx.x; i < T_LEN; i += MEGA_THREADS) {
        if (i < 3) { s[i] = -1; continue; }
        u64 fp = (u64)(unsigned)(sids[i - 3] + 1) * B3
               + (u64)(unsigned)(sids[i - 2] + 1) * B2
               + (u64)(unsigned)(sids[i - 1] + 1) * B1
               + (u64)(unsigned)(sids[i]     + 1);
        s[i] = (int)(fp & 0xFFFFull);
    }
    __syncthreads();

    int t = blockIdx.x * MEGA_THREADS + threadIdx.x;   // 0..4095 exact
    if (t < 3) {
        *(i32x4*)&idxs[t * 4] = (i32x4){0, 0, 0, 0};
        *(f32x4*)&vals[t * 4] = (f32x4){0.f, 0.f, 0.f, 0.f};
        return;
    }
    const int mys = s[t];

    // register-resident slot state
    u64 key = 0ull;
    int tk[TOP_M] = {0, 0, 0, 0};
    int cs[TOP_M] = {0, 0, 0, 0};
    bool dead = false;

    const i32x4* s4 = (const i32x4*)s;
    for (int qb = 0; qb < T_LEN / 4; qb += 8) {
        i32x4 v[8];
        #pragma unroll
        for (int u = 0; u < 8; ++u) v[u] = s4[qb + u];     // broadcast ds_read_b128 ×8
        bool any = false;
        #pragma unroll
        for (int u = 0; u < 8; ++u)
            any |= (v[u].x == mys) | (v[u].y == mys) | (v[u].z == mys) | (v[u].w == mys);
        if (!any) continue;

        #pragma unroll
        for (int u = 0; u < 8; ++u) {
            #pragma unroll
            for (int j = 0; j < 4; ++j) {
                int sv = (j == 0) ? v[u].x : (j == 1) ? v[u].y : (j == 2) ? v[u].z : v[u].w;
                if (sv != mys) continue;
                int tp = (qb + u) * 4 + j;
                if (tp < t) { dead = true; continue; }
                if (dead) continue;

                // ---- process chain member at position tp ----
                u64 wk = (u64)(unsigned)(sids[tp - 3] + 1) * B3
                       + (u64)(unsigned)(sids[tp - 2] + 1) * B2
                       + (u64)(unsigned)(sids[tp - 1] + 1) * B1
                       + (u64)(unsigned)(sids[tp]     + 1) + 1ull;
                bool key_match = (key == wk);

                int tot = 0;
                #pragma unroll
                for (int m = 0; m < TOP_M; ++m) tot += (tk[m] > 0) ? cs[m] : 0;
                bool emit = key_match && (tot > 0);
                float denom = fmaxf((float)tot, 1.0f);

                int   oi[TOP_M];
                float ov[TOP_M];
                #pragma unroll
                for (int m = 0; m < TOP_M; ++m) {
                    bool ok = emit && (tk[m] > 0) && (cs[m] > 0);
                    float p = fmaxf(1e-9f, (float)cs[m] / denom);
                    ov[m] = ok ? (logf(p) * WEIGHT) : 0.0f;
                    oi[m] = ok ? (tk[m] - 1) : 0;
                }
                *(i32x4*)&idxs[tp * 4] = (i32x4){oi[0], oi[1], oi[2], oi[3]};
                *(f32x4*)&vals[tp * 4] = (f32x4){ov[0], ov[1], ov[2], ov[3]};

                if (tp < T_LEN - 1) {                      // do_upd = active & has_next
                    if (!key_match) {
                        #pragma unroll
                        for (int m = 0; m < TOP_M; ++m) { tk[m] = 0; cs[m] = 0; }
                    }
                    key = wk;
                    int ntp1 = sids[tp + 1] + 1;

                    int ins = -1;
                    #pragma unroll
                    for (int m = 0; m < TOP_M; ++m) if (ins < 0 && tk[m] == ntp1) ins = m;
                    bool matched = (ins >= 0);
                    if (ins < 0) {
                        #pragma unroll
                        for (int m = 0; m < TOP_M; ++m) if (ins < 0 && tk[m] == 0) ins = m;
                    }
                    if (ins < 0) {
                        int best = cs[0]; ins = 0;
                        #pragma unroll
                        for (int m = 1; m < TOP_M; ++m) if (cs[m] < best) { best = cs[m]; ins = m; }
                    }
                    int cur = 0;
                    #pragma unroll
                    for (int m = 0; m < TOP_M; ++m) if (m == ins) cur = cs[m];
                    int new_cnt = matched ? min(65535, cur + 1) : 1;
                    #pragma unroll
                    for (int m = 0; m < TOP_M; ++m) if (m == ins) { tk[m] = ntp1; cs[m] = new_cnt; }
                }
            }
        }
        if (dead) break;   // not a head: everything after my first earlier twin is irrelevant
    }
}

// ---------------- Scatter: <=4 atomic adds per row, after copy completed ----------------
__global__ void scatter_kernel(const int* __restrict__ idxs,
                               const float* __restrict__ vals,
                               float* __restrict__ out) {
    int i = blockIdx.x * blockDim.x + threadIdx.x;
    if (i >= T_LEN * TOP_M) return;
    float v = vals[i];
    if (v != 0.0f) {
        int t = i / TOP_M;
        atomicAdd(out + (size_t)t * VOCAB + idxs[i], v);
    }
}

extern "C" void kernel_launch(void* const* d_in, const int* in_sizes, int n_in,
                              void* d_out, int out_size, void* d_ws, size_t ws_size,
                              hipStream_t stream) {
    const float* logits = (const float*)d_in[0];
    const int*   ids    = (const int*)d_in[1];
    float*       out    = (float*)d_out;

    char* ws = (char*)d_ws;
    int*   idxs = (int*)(ws);              // 16384*4 = 64 KB
    float* vals = (float*)(ws + 65536);    // 64 KB

    size_t n4 = (size_t)out_size / 4;      // 51,463,168 = 256 * 201,028 exact
    uint32_t copy_blocks = (uint32_t)((n4 + MEGA_THREADS - 1) / MEGA_THREADS);
    mega_kernel<<<CHAIN_BLOCKS + copy_blocks, MEGA_THREADS, 0, stream>>>(
        ids, (const f32x4*)logits, (f32x4*)out, n4, idxs, vals);

    scatter_kernel<<<(T_LEN * TOP_M + 255) / 256, 256, 0, stream>>>(idxs, vals, out);
}